// Round 4
// baseline (511.386 us; speedup 1.0000x reference)
//
#include <hip/hip_runtime.h>

typedef _Float16 half8 __attribute__((ext_vector_type(8)));
typedef float floatx4 __attribute__((ext_vector_type(4)));

#define NTOK 16384
#define DM   4096
#define NE   128
#define MT   32            // tokens per block
#define BK   64            // k per iter
#define KSPLIT 2
#define KHALF (DM / KSPLIT)       // 2048
#define NITER (KHALF / BK)        // 32
#define NBLK_MAIN (NTOK / MT * KSPLIT)  // 1024
#define ET   64                   // tokens per epilogue block
#define NBLK_EPI (NTOK / ET)      // 256
#define TEMP 0.3f

// ---------------- prep: pack wg into MFMA b-fragment order, f16x2 split ----------------
// tile tg = kchunk*8 + egroup; per tile 2048 B: [b1: 64 lanes x 16B][b2: ...].
// Lane l, half j holds wg[(egroup*16 + (l&15))*DM + kchunk*32 + (l>>4)*8 + j].
__global__ void pack_b_kernel(const float* __restrict__ wg, _Float16* __restrict__ Bp) {
    int gtid = blockIdx.x * blockDim.x + threadIdx.x;
    int l  = gtid & 63;
    int tg = gtid >> 6;
    int g  = tg & 7;
    int kc = tg >> 3;
    const float* src = wg + (size_t)(g * 16 + (l & 15)) * DM + kc * 32 + (l >> 4) * 8;
    float4 v0 = *(const float4*)src;
    float4 v1 = *(const float4*)(src + 4);
    float f[8] = {v0.x, v0.y, v0.z, v0.w, v1.x, v1.y, v1.z, v1.w};
    half8 h1, h2;
#pragma unroll
    for (int j = 0; j < 8; j++) {
        h1[j] = (_Float16)f[j];
        h2[j] = (_Float16)((f[j] - (float)h1[j]) * 2048.0f);
    }
    char* dst = (char*)Bp + (size_t)tg * 2048 + l * 16;
    *(half8*)dst = h1;
    *(half8*)(dst + 1024) = h2;
}

// ---------------- main GEMM: barrier-free, no LDS, direct global->reg A ----------------
__launch_bounds__(256, 4)
__global__ void moe_gemm_kernel(const float* __restrict__ A,
                                const _Float16* __restrict__ Bp,
                                float* __restrict__ part) {
    const int tid  = threadIdx.x;
    const int wave = tid >> 6;
    const int lane = tid & 63;
    const int quad = lane >> 4;
    const int lrow = lane & 15;
    const int hf   = blockIdx.x & 1;
    const int tok0 = (blockIdx.x >> 1) * MT;

    // A row pointers for this lane (rows r*16+lrow, k base = half*KHALF + quad*8)
    const float* ar0 = A + (size_t)(tok0 + lrow) * DM + hf * KHALF + quad * 8;
    const float* ar1 = ar0 + (size_t)16 * DM;
    // B fragment base for this wave (expert groups wave*2, wave*2+1)
    const char* bB = (const char*)Bp + (size_t)hf * (1u << 20) + (wave * 2) * 2048 + lane * 16;

    floatx4 accm[2][2], accc[2][2];
#pragma unroll
    for (int r = 0; r < 2; r++)
#pragma unroll
        for (int c = 0; c < 2; c++) {
            accm[r][c] = (floatx4){0.f, 0.f, 0.f, 0.f};
            accc[r][c] = (floatx4){0.f, 0.f, 0.f, 0.f};
        }

    for (int it = 0; it < NITER; ++it) {
        const int kbase = it * BK;
        // issue all 8 A loads up front (cold HBM; give them the whole iter to land)
        float4 av[2][2][2];
#pragma unroll
        for (int r = 0; r < 2; r++) {
            const float* ar = r ? ar1 : ar0;
#pragma unroll
            for (int ks = 0; ks < 2; ks++) {
                av[r][ks][0] = *(const float4*)(ar + kbase + ks * 32);
                av[r][ks][1] = *(const float4*)(ar + kbase + ks * 32 + 4);
            }
        }
        const char* bit = bB + (size_t)it * 32768;

#pragma unroll
        for (int ks = 0; ks < 2; ++ks) {
            half8 b1f[2], b2f[2];
#pragma unroll
            for (int c = 0; c < 2; c++) {
                b1f[c] = *(const half8*)(bit + ks * 16384 + c * 2048);
                b2f[c] = *(const half8*)(bit + ks * 16384 + c * 2048 + 1024);
            }
            half8 a1[2], a2[2];
#pragma unroll
            for (int r = 0; r < 2; r++) {
                float f[8] = {av[r][ks][0].x, av[r][ks][0].y, av[r][ks][0].z, av[r][ks][0].w,
                              av[r][ks][1].x, av[r][ks][1].y, av[r][ks][1].z, av[r][ks][1].w};
#pragma unroll
                for (int j = 0; j < 8; j++) {
                    a1[r][j] = (_Float16)f[j];
                    a2[r][j] = (_Float16)((f[j] - (float)a1[r][j]) * 2048.0f);
                }
            }
#pragma unroll
            for (int r = 0; r < 2; r++)
#pragma unroll
                for (int c = 0; c < 2; c++) {
                    accm[r][c] = __builtin_amdgcn_mfma_f32_16x16x32_f16(a1[r], b1f[c], accm[r][c], 0, 0, 0);
                    accc[r][c] = __builtin_amdgcn_mfma_f32_16x16x32_f16(a1[r], b2f[c], accc[r][c], 0, 0, 0);
                    accc[r][c] = __builtin_amdgcn_mfma_f32_16x16x32_f16(a2[r], b1f[c], accc[r][c], 0, 0, 0);
                }
        }
    }

    // write partial logits: part[half][expert][token]
    float* pbase = part + (size_t)hf * NTOK * NE;
#pragma unroll
    for (int r = 0; r < 2; r++)
#pragma unroll
        for (int c = 0; c < 2; c++) {
            floatx4 v;
#pragma unroll
            for (int g = 0; g < 4; g++)
                v[g] = accm[r][c][g] + accc[r][c][g] * (1.0f / 2048.0f);
            int e = wave * 32 + c * 16 + lrow;
            int t = tok0 + r * 16 + quad * 4;
            *(floatx4*)(pbase + (size_t)e * NTOK + t) = v;
        }
}

// ---------------- epilogue: sum halves, top-2, softmax, me/ce partials ----------------
__global__ void topk_kernel(const float* __restrict__ part,
                            float* __restrict__ out,
                            float* __restrict__ me_part,
                            float* __restrict__ ce_part) {
    __shared__ float LG[NE * 68];
    __shared__ float tmax[ET], tscale[ET];
    __shared__ int hist[NE];
    const int tid = threadIdx.x;
    const int t0  = blockIdx.x * ET;
    const float* p0 = part;
    const float* p1 = part + (size_t)NTOK * NE;

    {
        const int q = tid & 3;
#pragma unroll
        for (int pass = 0; pass < 2; pass++) {
            int e = (tid >> 2) + pass * 64;
            const float* r0 = p0 + (size_t)e * NTOK + t0 + q * 16;
            const float* r1 = p1 + (size_t)e * NTOK + t0 + q * 16;
            float* dst = LG + e * 68 + q * 16;
#pragma unroll
            for (int j = 0; j < 16; j += 4) {
                float4 a = *(const float4*)(r0 + j);
                float4 b = *(const float4*)(r1 + j);
                float4 s = {a.x + b.x, a.y + b.y, a.z + b.z, a.w + b.w};
                *(float4*)(dst + j) = s;
            }
        }
    }
    if (tid < NE) hist[tid] = 0;
    __syncthreads();

    if (tid < ET) {
        const int t = tid;
        float m1 = -1e30f, m2 = -1e30f;
        int i1 = 0, i2 = 0;
        for (int e = 0; e < NE; e++) {
            float v = LG[e * 68 + t];
            if (v > m1) { m2 = m1; i2 = i1; m1 = v; i1 = e; }
            else if (v > m2) { m2 = v; i2 = e; }
        }
        float s = 0.f;
        for (int e = 0; e < NE; e++)
            s += __expf((LG[e * 68 + t] - m1) * (1.0f / TEMP));
        tmax[t] = m1;
        tscale[t] = 1.0f / s;
        atomicAdd(&hist[i1], 1);

        const int tg = t0 + t;
        out[tg * 2 + 0] = (float)i1;
        out[tg * 2 + 1] = (float)i2;
        float d = __expf(m2 - m1);
        float g1 = 1.0f / (1.0f + d);
        out[2 * NTOK + tg * 2 + 0] = g1;
        out[2 * NTOK + tg * 2 + 1] = d * g1;
    }
    __syncthreads();

    if (tid < NE) {
        const int e = tid;
        float s = 0.f;
        for (int t = 0; t < ET; t++)
            s += __expf((LG[e * 68 + t] - tmax[t]) * (1.0f / TEMP)) * tscale[t];
        me_part[blockIdx.x * NE + e] = s;
        ce_part[blockIdx.x * NE + e] = (float)hist[e];
    }
}

// ---------------- finalize: reduce partials, loss ----------------
__global__ void finalize_kernel(const float* __restrict__ mp, const float* __restrict__ cp,
                                float* __restrict__ out) {
    __shared__ float red[2 * 8 * 128];
    __shared__ float wsum[2];
    const int tid = threadIdx.x;        // 1024
    const int e = tid & 127, seg = tid >> 7;
    float sm = 0.f, sc = 0.f;
    for (int b = seg; b < NBLK_EPI; b += 8) {
        sm += mp[b * NE + e];
        sc += cp[b * NE + e];
    }
    red[seg * 128 + e] = sm;
    red[1024 + seg * 128 + e] = sc;
    __syncthreads();
    if (tid < 128) {
        float me = 0.f, ce = 0.f;
#pragma unroll
        for (int s = 0; s < 8; s++) {
            me += red[s * 128 + tid];
            ce += red[1024 + s * 128 + tid];
        }
        ce *= (float)NE / (float)NTOK;
        float v = me * ce;
#pragma unroll
        for (int off = 32; off; off >>= 1) v += __shfl_down(v, off);
        if ((tid & 63) == 0) wsum[tid >> 6] = v;
    }
    __syncthreads();
    if (tid == 0) out[4 * NTOK] = (wsum[0] + wsum[1]) / (float)NTOK;
}

extern "C" void kernel_launch(void* const* d_in, const int* in_sizes, int n_in,
                              void* d_out, int out_size, void* d_ws, size_t ws_size,
                              hipStream_t stream) {
    (void)in_sizes; (void)n_in; (void)out_size; (void)ws_size;
    const float* inp = (const float*)d_in[0];
    const float* wg  = (const float*)d_in[1];
    float* out = (float*)d_out;

    _Float16* Bp = (_Float16*)d_ws;                              // 2 MB packed B
    float* part = (float*)((char*)d_ws + (2u << 20));            // 16 MB partial logits
    float* mp = (float*)((char*)d_ws + (18u << 20));             // 128 KB
    float* cp = mp + NBLK_EPI * NE;                              // 128 KB

    pack_b_kernel<<<256, 256, 0, stream>>>(wg, Bp);
    moe_gemm_kernel<<<NBLK_MAIN, 256, 0, stream>>>(inp, Bp, part);
    topk_kernel<<<NBLK_EPI, 256, 0, stream>>>(part, out, mp, cp);
    finalize_kernel<<<1, 1024, 0, stream>>>(mp, cp, out);
}